// Round 11
// baseline (120.792 us; speedup 1.0000x reference)
//
#include <hip/hip_runtime.h>
#include <math.h>

#define N_TOK 4096
#define DMODEL 512
#define NHEAD 8
#define DHEAD 64
#define CTX 10
#define NROW 8192  // B * N_TOK

typedef __bf16 bf16x4 __attribute__((ext_vector_type(4)));
typedef __bf16 bf16x8 __attribute__((ext_vector_type(8)));
typedef float  f32x4  __attribute__((ext_vector_type(4)));

#define GLOAD_LDS16(g, l) __builtin_amdgcn_global_load_lds(                 \
    (const __attribute__((address_space(1))) void*)(g),                     \
    (__attribute__((address_space(3))) void*)(l), 16, 0, 0)

// ---------------------------------------------------------------------------
// Merged weight transpose-convert:
//   blocks [0,128):  Wq|Wv [h][k=512][kk=64] fp32 -> Wtqv[n=1024][k=512] bf16
//   blocks [128,192): Wup [k=512][n=512] fp32     -> Wtup[n=512][k=512] bf16
// ---------------------------------------------------------------------------
__global__ __launch_bounds__(256) void conv_w(const float* __restrict__ Wq,
                                              const float* __restrict__ Wv,
                                              const float* __restrict__ Wup,
                                              __bf16* __restrict__ Wtqv,
                                              __bf16* __restrict__ Wtup)
{
    __shared__ float T[64][65];
    const int tid = threadIdx.x;
    const int bid = blockIdx.x;

    const float* src;
    __bf16* dstBase;
    int k0, rowBase, srcStride;
    if (bid < 128) {
        k0 = (bid & 7) * 64;
        const int h   = (bid >> 3) & 7;
        const int mat = bid >> 6;
        src = (mat ? Wv : Wq) + (size_t)h * DMODEL * DHEAD;
        dstBase = Wtqv;
        rowBase = mat * 512 + h * 64;
        srcStride = DHEAD;
    } else {
        const int b2 = bid - 128;
        k0 = (b2 & 7) * 64;
        const int n0 = (b2 >> 3) * 64;
        src = Wup + n0;
        dstBase = Wtup;
        rowBase = n0;
        srcStride = DMODEL;
    }

#pragma unroll
    for (int it = 0; it < 4; it++) {
        const int kr = it * 16 + (tid >> 4);
        const int c4 = (tid & 15) * 4;
        const float4 v = *(const float4*)(src + (size_t)(k0 + kr) * srcStride + c4);
        T[kr][c4 + 0] = v.x; T[kr][c4 + 1] = v.y;
        T[kr][c4 + 2] = v.z; T[kr][c4 + 3] = v.w;
    }
    __syncthreads();
    const int c   = tid >> 2;
    const int kk0 = (tid & 3) * 16;
    __bf16* dst = dstBase + (size_t)(rowBase + c) * DMODEL + k0 + kk0;
    bf16x8 o0, o1;
#pragma unroll
    for (int j = 0; j < 8; j++) o0[j] = (__bf16)T[kk0 + j][c];
#pragma unroll
    for (int j = 0; j < 8; j++) o1[j] = (__bf16)T[kk0 + 8 + j][c];
    *(bf16x8*)dst = o0;
    *(bf16x8*)(dst + 8) = o1;
}

// ---------------------------------------------------------------------------
// Stage 1: MFMA GEMM  x[8192x512]fp32 @ Wt^T -> Qt, Vt bf16 dim-major.
// Round-11 change: BK=64 (8 K-iters instead of 16). Halves the number of
// barrier drains — the m97-structure stall — and doubles MFMA work per
// drain (16/iter). LDS 24 KB (As 128x64 + Bs 64x64). kc is the OUTER
// fragment loop so k-accumulation order is bit-identical to BK=32.
// XCD swizzle: row = bid & 63 -> all 16 col-blocks of a row-tile on 1 XCD.
// ---------------------------------------------------------------------------
__global__ __launch_bounds__(256) void gemm_qv_mfma(
    const float* __restrict__ x,
    const __bf16* __restrict__ Wt,
    __bf16* __restrict__ Qt,
    __bf16* __restrict__ Vt)
{
    __shared__ __align__(16) __bf16 As[128 * 64];   // 16 KB
    __shared__ __align__(16) __bf16 Bs[64 * 64];    //  8 KB

    const int tid  = threadIdx.x;
    const int w    = tid >> 6;
    const int lane = tid & 63;
    const int lm   = lane & 15;
    const int q    = lane >> 4;
    const int bid  = blockIdx.x;
    const int row0 = (bid & 63) * 128;     // XCD-swizzled
    const int col0 = (bid >> 6) * 64;      // 16 col-tiles

    // A staging: row = p*32 + (tid>>3), k floats [(tid&7)*8, +8) -> 8 lanes
    // cover a full 256 B row segment (fully coalesced), 4 row-passes.
    const int ar = tid >> 3;           // 0..31
    const int ac = (tid & 7) * 8;      // 0..56
    const float* gA = x + (size_t)(row0 + ar) * DMODEL + ac;

    // B staging: 2 DMA issues of 32 rows x 64 k bf16. LDS dest is
    // wave-uniform base + lane*16 (DMA constraint): tid*16 B == w*1024 + lane*16.
    const __bf16* gB = Wt + (size_t)(col0 + (tid >> 3)) * DMODEL + (tid & 7) * 8;
    __bf16* lB0 = Bs + w * 512;            // elems; +lane*16B implicit
    __bf16* lB1 = Bs + 2048 + w * 512;     // rows 32..63

    f32x4 acc[2][4];
#pragma unroll
    for (int i = 0; i < 2; i++)
#pragma unroll
        for (int j = 0; j < 4; j++) acc[i][j] = (f32x4){0.f, 0.f, 0.f, 0.f};

    for (int k0 = 0; k0 < DMODEL; k0 += 64) {
        float4 a[8];
#pragma unroll
        for (int p = 0; p < 4; p++) {
            a[2 * p]     = *(const float4*)(gA + (size_t)p * 32 * DMODEL);
            a[2 * p + 1] = *(const float4*)(gA + (size_t)p * 32 * DMODEL + 4);
        }
        gA += 64;

        __syncthreads();               // prev iteration's LDS reads complete
#pragma unroll
        for (int p = 0; p < 4; p++) {
            bf16x8 o;
            o[0] = (__bf16)a[2 * p].x;     o[1] = (__bf16)a[2 * p].y;
            o[2] = (__bf16)a[2 * p].z;     o[3] = (__bf16)a[2 * p].w;
            o[4] = (__bf16)a[2 * p + 1].x; o[5] = (__bf16)a[2 * p + 1].y;
            o[6] = (__bf16)a[2 * p + 1].z; o[7] = (__bf16)a[2 * p + 1].w;
            *(bf16x8*)&As[(ar + p * 32) * 64 + ac] = o;
        }
        GLOAD_LDS16(gB, lB0);
        GLOAD_LDS16(gB + 32 * DMODEL, lB1);
        gB += 64;
        __syncthreads();               // drains vmcnt + lgkmcnt

#pragma unroll
        for (int kc = 0; kc < 2; kc++) {   // kc OUTER: keeps k-order == BK=32
            bf16x8 af[2], bfr[4];
#pragma unroll
            for (int mi = 0; mi < 2; mi++)
                af[mi] = *(const bf16x8*)&As[(w * 32 + mi * 16 + lm) * 64 + kc * 32 + q * 8];
#pragma unroll
            for (int ni = 0; ni < 4; ni++)
                bfr[ni] = *(const bf16x8*)&Bs[(ni * 16 + lm) * 64 + kc * 32 + q * 8];
#pragma unroll
            for (int mi = 0; mi < 2; mi++)
#pragma unroll
                for (int ni = 0; ni < 4; ni++)
                    acc[mi][ni] = __builtin_amdgcn_mfma_f32_16x16x32_bf16(
                        af[mi], bfr[ni], acc[mi][ni], 0, 0, 0);
        }
    }

    // Epilogue: bf16 dim-major scatter [bb*512+cc][token]
#pragma unroll
    for (int ni = 0; ni < 4; ni++) {
        const int c  = col0 + ni * 16 + lm;
        const int cc = c & 511;
        __bf16* outB = (c < 512 ? Qt : Vt);
#pragma unroll
        for (int mi = 0; mi < 2; mi++) {
            const int m  = row0 + w * 32 + mi * 16 + q * 4;
            const int bb = m >> 12;
            const int nt = m & (N_TOK - 1);
            bf16x4 o;
            o[0] = (__bf16)acc[mi][ni][0];
            o[1] = (__bf16)acc[mi][ni][1];
            o[2] = (__bf16)acc[mi][ni][2];
            o[3] = (__bf16)acc[mi][ni][3];
            *(bf16x4*)(outB + ((size_t)(bb * 512 + cc)) * N_TOK + nt) = o;
        }
    }
}

// ---------------------------------------------------------------------------
// Stage 2: banded attention, LDS-staged V band from bf16 Vt (round-8 form:
// 8-aligned halo tok0 = i0-16 so clamped chunks are fully-invalid only).
// ---------------------------------------------------------------------------
#define VSTRIDE 97
__global__ __launch_bounds__(256) void attn_band(
    const __bf16* __restrict__ Qt,
    const __bf16* __restrict__ Vt,
    __bf16* __restrict__ Hb16)
{
    __shared__ float Vs[64 * VSTRIDE];   // 24,832 B

    const int tid  = threadIdx.x;
    const int bh   = blockIdx.x >> 6;
    const int tile = blockIdx.x & 63;
    const int i0   = tile * 64;
    const int b    = bh >> 3;
    const int h    = bh & 7;

    const __bf16* vband = Vt + (size_t)bh * DHEAD * N_TOK;
    const int tok0 = i0 - 16;
#pragma unroll
    for (int it = 0; it < 3; it++) {
        const int idx = it * 256 + tid;        // 0..767
        const int k   = idx / 12;              // dim
        const int s8  = idx - k * 12;          // 8-token chunk, 8-aligned
        const int tokg = tok0 + s8 * 8;
        const int tokc = min(max(tokg, 0), N_TOK - 8);
        const bf16x8 v = *(const bf16x8*)(vband + (size_t)k * N_TOK + tokc);
        float* dst = &Vs[k * VSTRIDE + s8 * 8];
#pragma unroll
        for (int e = 0; e < 8; e++) dst[e] = (float)v[e];
    }

    const int lane = tid & 63;
    const int wv   = tid >> 6;
    const int il   = lane & 15;
    const int p    = lane >> 4;
    const int i    = i0 + wv * 16 + il;
    const int slot0 = wv * 16 + il + 6;        // slot of tap d=0 (j=i-10)

    const __bf16* qbase = Qt + ((size_t)bh * DHEAD + p * 16) * N_TOK;
    float qv[16];
#pragma unroll
    for (int k = 0; k < 16; k++) qv[k] = (float)qbase[(size_t)k * N_TOK + i];

    __syncthreads();

    float c[16];
#pragma unroll
    for (int k = 0; k < 16; k++) c[k] = 0.f;
    float Z = 0.f;

#pragma unroll 3
    for (int d = 0; d < 2 * CTX + 1; d++) {
        const float* vrow = &Vs[p * 16 * VSTRIDE + slot0 + d];
        float v[16];
#pragma unroll
        for (int k = 0; k < 16; k++) v[k] = vrow[k * VSTRIDE];
        float s = 0.f;
#pragma unroll
        for (int k = 0; k < 16; k++) s += qv[k] * v[k];
        s += __shfl_xor(s, 16, 64);
        s += __shfl_xor(s, 32, 64);

        const int j = i + d - CTX;
        const bool valid = (d != CTX) && (j >= 0) && (j < N_TOK);
        const float w = valid ? __expf(s * 0.0625f) : 0.f;
        Z += w;
#pragma unroll
        for (int k = 0; k < 16; k++) c[k] += w * v[k];
    }

    const float inv = 1.f / Z;
    __bf16* dst = Hb16 + ((size_t)(b * N_TOK + i)) * DMODEL + h * DHEAD + p * 16;
    bf16x8 o0, o1;
#pragma unroll
    for (int k = 0; k < 8; k++) o0[k] = (__bf16)(c[k] * inv);
#pragma unroll
    for (int k = 0; k < 8; k++) o1[k] = (__bf16)(c[8 + k] * inv);
    *(bf16x8*)dst = o0;
    *(bf16x8*)(dst + 8) = o1;
}

// ---------------------------------------------------------------------------
// Stage 3: MFMA GEMM  Hb16[8192x512] @ Wup -> out fp32 [8192x512].
// BK=64 (8 K-iters), all-DMA staging: A 4 issues, B 2 issues per iter.
// XCD swizzle: row = bid & 63, col = bid >> 6 (8 col-tiles of 64).
// ---------------------------------------------------------------------------
__global__ __launch_bounds__(256) void gemm_out_mfma(
    const __bf16* __restrict__ Hb,
    const __bf16* __restrict__ Wt,
    float* __restrict__ out)
{
    __shared__ __align__(16) __bf16 As[128 * 64];   // 16 KB
    __shared__ __align__(16) __bf16 Bs[64 * 64];    //  8 KB

    const int tid  = threadIdx.x;
    const int w    = tid >> 6;
    const int lane = tid & 63;
    const int lm   = lane & 15;
    const int q    = lane >> 4;
    const int bid  = blockIdx.x;
    const int row0 = (bid & 63) * 128;     // XCD-swizzled
    const int col0 = (bid >> 6) * 64;

    // staging maps: row = p*32 + (tid>>3), k seg = (tid&7)*8 (16 B)
    const __bf16* gA = Hb + (size_t)(row0 + (tid >> 3)) * DMODEL + (tid & 7) * 8;
    const __bf16* gB = Wt + (size_t)(col0 + (tid >> 3)) * DMODEL + (tid & 7) * 8;
    __bf16* lA0 = As + w * 512;            // +lane*16B implicit per DMA
    __bf16* lB0 = Bs + w * 512;

    f32x4 acc[2][4];
#pragma unroll
    for (int i = 0; i < 2; i++)
#pragma unroll
        for (int j = 0; j < 4; j++) acc[i][j] = (f32x4){0.f, 0.f, 0.f, 0.f};

    for (int k0 = 0; k0 < DMODEL; k0 += 64) {
        __syncthreads();
#pragma unroll
        for (int p = 0; p < 4; p++)
            GLOAD_LDS16(gA + (size_t)p * 32 * DMODEL, lA0 + p * 2048);
        GLOAD_LDS16(gB, lB0);
        GLOAD_LDS16(gB + (size_t)32 * DMODEL, lB0 + 2048);
        gA += 64; gB += 64;
        __syncthreads();

#pragma unroll
        for (int kc = 0; kc < 2; kc++) {
            bf16x8 af[2], bfr[4];
#pragma unroll
            for (int mi = 0; mi < 2; mi++)
                af[mi] = *(const bf16x8*)&As[(w * 32 + mi * 16 + lm) * 64 + kc * 32 + q * 8];
#pragma unroll
            for (int ni = 0; ni < 4; ni++)
                bfr[ni] = *(const bf16x8*)&Bs[(ni * 16 + lm) * 64 + kc * 32 + q * 8];
#pragma unroll
            for (int mi = 0; mi < 2; mi++)
#pragma unroll
                for (int ni = 0; ni < 4; ni++)
                    acc[mi][ni] = __builtin_amdgcn_mfma_f32_16x16x32_bf16(
                        af[mi], bfr[ni], acc[mi][ni], 0, 0, 0);
        }
    }

#pragma unroll
    for (int mi = 0; mi < 2; mi++) {
        const int m0 = row0 + w * 32 + mi * 16 + q * 4;
#pragma unroll
        for (int ni = 0; ni < 4; ni++) {
            const int n = col0 + ni * 16 + lm;
#pragma unroll
            for (int r = 0; r < 4; r++)
                out[(size_t)(m0 + r) * DMODEL + n] = acc[mi][ni][r];
        }
    }
}

// ---------------------------------------------------------------------------
extern "C" void kernel_launch(void* const* d_in, const int* in_sizes, int n_in,
                              void* d_out, int out_size, void* d_ws, size_t ws_size,
                              hipStream_t stream)
{
    const float* x   = (const float*)d_in[0];
    const float* Wq  = (const float*)d_in[1];
    const float* Wv  = (const float*)d_in[2];
    const float* Wup = (const float*)d_in[3];
    float* out = (float*)d_out;

    const size_t QV = (size_t)2 * NHEAD * N_TOK * DHEAD;   // 4,194,304 elems
    __bf16* Qt   = (__bf16*)d_ws;                          // 8.39 MB
    __bf16* Vt   = Qt + QV;                                // 8.39 MB
    __bf16* Hb16 = Vt + QV;                                // 8.39 MB
    __bf16* Wtqv = Hb16 + (size_t)NROW * DMODEL;           // 1.05 MB
    __bf16* Wtup = Wtqv + (size_t)1024 * DMODEL;           // 0.52 MB

    dim3 blk(256);
    conv_w       <<<dim3(192),  blk, 0, stream>>>(Wq, Wv, Wup, Wtqv, Wtup);
    gemm_qv_mfma <<<dim3(1024), blk, 0, stream>>>(x, Wtqv, Qt, Vt);
    attn_band    <<<dim3(1024), blk, 0, stream>>>(Qt, Vt, Hb16);
    gemm_out_mfma<<<dim3(512),  blk, 0, stream>>>(Hb16, Wtup, out);
}

// Round 12
// 119.966 us; speedup vs baseline: 1.0069x; 1.0069x over previous
//
#include <hip/hip_runtime.h>
#include <math.h>

#define N_TOK 4096
#define DMODEL 512
#define NHEAD 8
#define DHEAD 64
#define CTX 10
#define NROW 8192  // B * N_TOK

typedef __bf16 bf16x4 __attribute__((ext_vector_type(4)));
typedef __bf16 bf16x8 __attribute__((ext_vector_type(8)));
typedef float  f32x4  __attribute__((ext_vector_type(4)));

#define GLOAD_LDS16(g, l) __builtin_amdgcn_global_load_lds(                 \
    (const __attribute__((address_space(1))) void*)(g),                     \
    (__attribute__((address_space(3))) void*)(l), 16, 0, 0)

// ---------------------------------------------------------------------------
// Merged weight transpose-convert:
//   blocks [0,128):  Wq|Wv [h][k=512][kk=64] fp32 -> Wtqv[n=1024][k=512] bf16
//   blocks [128,192): Wup [k=512][n=512] fp32     -> Wtup[n=512][k=512] bf16
// ---------------------------------------------------------------------------
__global__ __launch_bounds__(256) void conv_w(const float* __restrict__ Wq,
                                              const float* __restrict__ Wv,
                                              const float* __restrict__ Wup,
                                              __bf16* __restrict__ Wtqv,
                                              __bf16* __restrict__ Wtup)
{
    __shared__ float T[64][65];
    const int tid = threadIdx.x;
    const int bid = blockIdx.x;

    const float* src;
    __bf16* dstBase;
    int k0, rowBase, srcStride;
    if (bid < 128) {
        k0 = (bid & 7) * 64;
        const int h   = (bid >> 3) & 7;
        const int mat = bid >> 6;
        src = (mat ? Wv : Wq) + (size_t)h * DMODEL * DHEAD;
        dstBase = Wtqv;
        rowBase = mat * 512 + h * 64;
        srcStride = DHEAD;
    } else {
        const int b2 = bid - 128;
        k0 = (b2 & 7) * 64;
        const int n0 = (b2 >> 3) * 64;
        src = Wup + n0;
        dstBase = Wtup;
        rowBase = n0;
        srcStride = DMODEL;
    }

#pragma unroll
    for (int it = 0; it < 4; it++) {
        const int kr = it * 16 + (tid >> 4);
        const int c4 = (tid & 15) * 4;
        const float4 v = *(const float4*)(src + (size_t)(k0 + kr) * srcStride + c4);
        T[kr][c4 + 0] = v.x; T[kr][c4 + 1] = v.y;
        T[kr][c4 + 2] = v.z; T[kr][c4 + 3] = v.w;
    }
    __syncthreads();
    const int c   = tid >> 2;
    const int kk0 = (tid & 3) * 16;
    __bf16* dst = dstBase + (size_t)(rowBase + c) * DMODEL + k0 + kk0;
    bf16x8 o0, o1;
#pragma unroll
    for (int j = 0; j < 8; j++) o0[j] = (__bf16)T[kk0 + j][c];
#pragma unroll
    for (int j = 0; j < 8; j++) o1[j] = (__bf16)T[kk0 + 8 + j][c];
    *(bf16x8*)dst = o0;
    *(bf16x8*)(dst + 8) = o1;
}

// ---------------------------------------------------------------------------
// Stage 1: MFMA GEMM  x[8192x512]fp32 @ Wt^T -> Qt, Vt bf16 dim-major.
// Best-measured config (round 10): BK=32, 128x64 tile, grid 1024 (4 blk/CU).
// BK=64 variant regressed (−2 µs): drain cost tracks the last-issued load's
// latency, not barrier count; wider A-batches lengthen that chain.
// XCD swizzle: row = bid & 63 -> all 16 col-blocks of a row-tile on 1 XCD.
// ---------------------------------------------------------------------------
__global__ __launch_bounds__(256) void gemm_qv_mfma(
    const float* __restrict__ x,
    const __bf16* __restrict__ Wt,
    __bf16* __restrict__ Qt,
    __bf16* __restrict__ Vt)
{
    __shared__ __align__(16) __bf16 As[128 * 32];
    __shared__ __align__(16) __bf16 Bs[64 * 32];

    const int tid  = threadIdx.x;
    const int w    = tid >> 6;
    const int lane = tid & 63;
    const int lm   = lane & 15;
    const int q    = lane >> 4;
    const int bid  = blockIdx.x;
    const int row0 = (bid & 63) * 128;     // XCD-swizzled
    const int col0 = (bid >> 6) * 64;      // 16 col-tiles

    const int asr = tid >> 3;          // 0..31 row within pass
    const int asc = (tid & 7) * 4;     // k float offset
    const float* gA = x + (size_t)(row0 + asr) * DMODEL + asc;

    const int sr = lane >> 2;          // 0..15
    const int sc = (lane & 3) * 8;
    const __bf16* gB0 = Wt + (size_t)(col0 + w * 16 + sr) * DMODEL + sc;
    __bf16* lB0 = Bs + (w * 16) * 32;

    f32x4 acc[2][4];
#pragma unroll
    for (int i = 0; i < 2; i++)
#pragma unroll
        for (int j = 0; j < 4; j++) acc[i][j] = (f32x4){0.f, 0.f, 0.f, 0.f};

    for (int k0 = 0; k0 < DMODEL; k0 += 32) {
        float4 a[4];
#pragma unroll
        for (int p = 0; p < 4; p++)
            a[p] = *(const float4*)(gA + (size_t)p * 32 * DMODEL);
        gA += 32;

        __syncthreads();
#pragma unroll
        for (int p = 0; p < 4; p++) {
            bf16x4 o;
            o[0] = (__bf16)a[p].x; o[1] = (__bf16)a[p].y;
            o[2] = (__bf16)a[p].z; o[3] = (__bf16)a[p].w;
            *(bf16x4*)&As[(asr + p * 32) * 32 + asc] = o;
        }
        GLOAD_LDS16(gB0, lB0);
        gB0 += 32;
        __syncthreads();

        bf16x8 af[2], bfr[4];
#pragma unroll
        for (int mi = 0; mi < 2; mi++)
            af[mi] = *(const bf16x8*)&As[(w * 32 + mi * 16 + lm) * 32 + q * 8];
#pragma unroll
        for (int ni = 0; ni < 4; ni++)
            bfr[ni] = *(const bf16x8*)&Bs[(ni * 16 + lm) * 32 + q * 8];
#pragma unroll
        for (int mi = 0; mi < 2; mi++)
#pragma unroll
            for (int ni = 0; ni < 4; ni++)
                acc[mi][ni] = __builtin_amdgcn_mfma_f32_16x16x32_bf16(
                    af[mi], bfr[ni], acc[mi][ni], 0, 0, 0);
    }

    // Epilogue: bf16 dim-major scatter [bb*512+cc][token]
#pragma unroll
    for (int ni = 0; ni < 4; ni++) {
        const int c  = col0 + ni * 16 + lm;
        const int cc = c & 511;
        __bf16* outB = (c < 512 ? Qt : Vt);
#pragma unroll
        for (int mi = 0; mi < 2; mi++) {
            const int m  = row0 + w * 32 + mi * 16 + q * 4;
            const int bb = m >> 12;
            const int nt = m & (N_TOK - 1);
            bf16x4 o;
            o[0] = (__bf16)acc[mi][ni][0];
            o[1] = (__bf16)acc[mi][ni][1];
            o[2] = (__bf16)acc[mi][ni][2];
            o[3] = (__bf16)acc[mi][ni][3];
            *(bf16x4*)(outB + ((size_t)(bb * 512 + cc)) * N_TOK + nt) = o;
        }
    }
}

// ---------------------------------------------------------------------------
// Stage 2: banded attention, LDS-staged V band from bf16 Vt (round-8 form:
// 8-aligned halo tok0 = i0-16 so clamped chunks are fully-invalid only).
// ---------------------------------------------------------------------------
#define VSTRIDE 97
__global__ __launch_bounds__(256) void attn_band(
    const __bf16* __restrict__ Qt,
    const __bf16* __restrict__ Vt,
    __bf16* __restrict__ Hb16)
{
    __shared__ float Vs[64 * VSTRIDE];   // 24,832 B

    const int tid  = threadIdx.x;
    const int bh   = blockIdx.x >> 6;
    const int tile = blockIdx.x & 63;
    const int i0   = tile * 64;
    const int b    = bh >> 3;
    const int h    = bh & 7;

    const __bf16* vband = Vt + (size_t)bh * DHEAD * N_TOK;
    const int tok0 = i0 - 16;
#pragma unroll
    for (int it = 0; it < 3; it++) {
        const int idx = it * 256 + tid;        // 0..767
        const int k   = idx / 12;              // dim
        const int s8  = idx - k * 12;          // 8-token chunk, 8-aligned
        const int tokg = tok0 + s8 * 8;
        const int tokc = min(max(tokg, 0), N_TOK - 8);
        const bf16x8 v = *(const bf16x8*)(vband + (size_t)k * N_TOK + tokc);
        float* dst = &Vs[k * VSTRIDE + s8 * 8];
#pragma unroll
        for (int e = 0; e < 8; e++) dst[e] = (float)v[e];
    }

    const int lane = tid & 63;
    const int wv   = tid >> 6;
    const int il   = lane & 15;
    const int p    = lane >> 4;
    const int i    = i0 + wv * 16 + il;
    const int slot0 = wv * 16 + il + 6;        // slot of tap d=0 (j=i-10)

    const __bf16* qbase = Qt + ((size_t)bh * DHEAD + p * 16) * N_TOK;
    float qv[16];
#pragma unroll
    for (int k = 0; k < 16; k++) qv[k] = (float)qbase[(size_t)k * N_TOK + i];

    __syncthreads();

    float c[16];
#pragma unroll
    for (int k = 0; k < 16; k++) c[k] = 0.f;
    float Z = 0.f;

#pragma unroll 3
    for (int d = 0; d < 2 * CTX + 1; d++) {
        const float* vrow = &Vs[p * 16 * VSTRIDE + slot0 + d];
        float v[16];
#pragma unroll
        for (int k = 0; k < 16; k++) v[k] = vrow[k * VSTRIDE];
        float s = 0.f;
#pragma unroll
        for (int k = 0; k < 16; k++) s += qv[k] * v[k];
        s += __shfl_xor(s, 16, 64);
        s += __shfl_xor(s, 32, 64);

        const int j = i + d - CTX;
        const bool valid = (d != CTX) && (j >= 0) && (j < N_TOK);
        const float w = valid ? __expf(s * 0.0625f) : 0.f;
        Z += w;
#pragma unroll
        for (int k = 0; k < 16; k++) c[k] += w * v[k];
    }

    const float inv = 1.f / Z;
    __bf16* dst = Hb16 + ((size_t)(b * N_TOK + i)) * DMODEL + h * DHEAD + p * 16;
    bf16x8 o0, o1;
#pragma unroll
    for (int k = 0; k < 8; k++) o0[k] = (__bf16)(c[k] * inv);
#pragma unroll
    for (int k = 0; k < 8; k++) o1[k] = (__bf16)(c[8 + k] * inv);
    *(bf16x8*)dst = o0;
    *(bf16x8*)(dst + 8) = o1;
}

// ---------------------------------------------------------------------------
// Stage 3: MFMA GEMM  Hb16[8192x512] @ Wup -> out fp32 [8192x512].
// XCD swizzle: row = bid & 63, col = bid >> 6 (8 col-tiles of 64).
// ---------------------------------------------------------------------------
__global__ __launch_bounds__(256) void gemm_out_mfma(
    const __bf16* __restrict__ Hb,
    const __bf16* __restrict__ Wt,
    float* __restrict__ out)
{
    __shared__ __align__(16) __bf16 As[128 * 32];
    __shared__ __align__(16) __bf16 Bs[64 * 32];

    const int tid  = threadIdx.x;
    const int w    = tid >> 6;
    const int lane = tid & 63;
    const int lm   = lane & 15;
    const int q    = lane >> 4;
    const int bid  = blockIdx.x;
    const int row0 = (bid & 63) * 128;     // XCD-swizzled
    const int col0 = (bid >> 6) * 64;

    const int sr = lane >> 2;
    const int sc = (lane & 3) * 8;
    const __bf16* gA0 = Hb + (size_t)(row0 + w * 32 +  0 + sr) * DMODEL + sc;
    const __bf16* gA1 = Hb + (size_t)(row0 + w * 32 + 16 + sr) * DMODEL + sc;
    const __bf16* gB0 = Wt + (size_t)(col0 + w * 16 + sr) * DMODEL + sc;
    __bf16* lA0 = As + (w * 32 +  0) * 32;
    __bf16* lA1 = As + (w * 32 + 16) * 32;
    __bf16* lB0 = Bs + (w * 16) * 32;

    f32x4 acc[2][4];
#pragma unroll
    for (int i = 0; i < 2; i++)
#pragma unroll
        for (int j = 0; j < 4; j++) acc[i][j] = (f32x4){0.f, 0.f, 0.f, 0.f};

    for (int k0 = 0; k0 < DMODEL; k0 += 32) {
        __syncthreads();
        GLOAD_LDS16(gA0, lA0); GLOAD_LDS16(gA1, lA1); GLOAD_LDS16(gB0, lB0);
        gA0 += 32; gA1 += 32; gB0 += 32;
        __syncthreads();

        bf16x8 af[2], bfr[4];
#pragma unroll
        for (int mi = 0; mi < 2; mi++)
            af[mi] = *(const bf16x8*)&As[(w * 32 + mi * 16 + lm) * 32 + q * 8];
#pragma unroll
        for (int ni = 0; ni < 4; ni++)
            bfr[ni] = *(const bf16x8*)&Bs[(ni * 16 + lm) * 32 + q * 8];
#pragma unroll
        for (int mi = 0; mi < 2; mi++)
#pragma unroll
            for (int ni = 0; ni < 4; ni++)
                acc[mi][ni] = __builtin_amdgcn_mfma_f32_16x16x32_bf16(
                    af[mi], bfr[ni], acc[mi][ni], 0, 0, 0);
    }

#pragma unroll
    for (int mi = 0; mi < 2; mi++) {
        const int m0 = row0 + w * 32 + mi * 16 + q * 4;
#pragma unroll
        for (int ni = 0; ni < 4; ni++) {
            const int n = col0 + ni * 16 + lm;
#pragma unroll
            for (int r = 0; r < 4; r++)
                out[(size_t)(m0 + r) * DMODEL + n] = acc[mi][ni][r];
        }
    }
}

// ---------------------------------------------------------------------------
extern "C" void kernel_launch(void* const* d_in, const int* in_sizes, int n_in,
                              void* d_out, int out_size, void* d_ws, size_t ws_size,
                              hipStream_t stream)
{
    const float* x   = (const float*)d_in[0];
    const float* Wq  = (const float*)d_in[1];
    const float* Wv  = (const float*)d_in[2];
    const float* Wup = (const float*)d_in[3];
    float* out = (float*)d_out;

    const size_t QV = (size_t)2 * NHEAD * N_TOK * DHEAD;   // 4,194,304 elems
    __bf16* Qt   = (__bf16*)d_ws;                          // 8.39 MB
    __bf16* Vt   = Qt + QV;                                // 8.39 MB
    __bf16* Hb16 = Vt + QV;                                // 8.39 MB
    __bf16* Wtqv = Hb16 + (size_t)NROW * DMODEL;           // 1.05 MB
    __bf16* Wtup = Wtqv + (size_t)1024 * DMODEL;           // 0.52 MB

    dim3 blk(256);
    conv_w       <<<dim3(192),  blk, 0, stream>>>(Wq, Wv, Wup, Wtqv, Wtup);
    gemm_qv_mfma <<<dim3(1024), blk, 0, stream>>>(x, Wtqv, Qt, Vt);
    attn_band    <<<dim3(1024), blk, 0, stream>>>(Qt, Vt, Hb16);
    gemm_out_mfma<<<dim3(512),  blk, 0, stream>>>(Hb16, Wtup, out);
}